// Round 28
// baseline (52.490 us; speedup 1.0000x reference)
//
#include <hip/hip_runtime.h>
#include <stdint.h>

// Three-kernel 3x3 neighborhood-attention — every kernel "apply-shaped"
// (no cross-wave reduce in any hot path; derived from the measured 3.8x
// per-VMEM efficiency gap between apply (19cyc) and fused (72cyc)).
//  K1 partial: 2048 ONE-WAVE no-LDS no-barrier blocks (row x ch-quarter).
//    R19's pass-A loop (16ch, float4 loads, shfl margins, S-collapse);
//    19 partial planes -> ws[q][plane][PIX] via coalesced float4 stores.
//  K2 reduce: 512 blocks; thread=pixel sums 4 partials (coalesced scalar
//    loads, L2/L3-hot), softmax, coefs overwrite the q=0 planes (safe:
//    per-thread read-before-write, pixels disjoint).
//  K3 apply: proven streaming kernel, coef = ws planes 0..8.
//  Fallback: R19 fused kernel if ws too small.
// Shapes: [b=2, c=64, h=256, w=256] fp32.

constexpr int C = 64, H = 256, W = 256, HW = H * W;
constexpr int B = 2, PIX = B * HW;

// ---------------- K1: partial kernel (1 wave, no LDS, no barriers) ----------------
__global__ __launch_bounds__(64) void partial_kernel(const float* __restrict__ nbr,
                                                     const float* __restrict__ ref,
                                                     float* __restrict__ ws) {
  const int lane = threadIdx.x;       // 0..63; quad index
  const int x0   = lane * 4;

  // XCD swizzle, bijective on [0,2048)
  const int bid = ((blockIdx.x & 7) << 8) | (blockIdx.x >> 3);
  const int q   = bid & 3;            // channel quarter
  const int by  = bid >> 2;           // b*256 + y
  const int b   = by >> 8;
  const int y   = by & 255;
  const int ym = (y == 0)     ? 1     : y - 1;   // jnp reflect
  const int yp = (y == H - 1) ? H - 2 : y + 1;

  const float* nbase = nbr + (size_t)b * C * HW;
  const float* rrow  = ref + (size_t)b * C * HW + y * W;
  const int oM = ym * W, oC = y * W, oP = yp * W;
  const int c0 = q * 16;

  float dt[4][9], s2[3][6], sr[4];
#pragma unroll
  for (int e = 0; e < 4; ++e) {
    sr[e] = 0.f;
#pragma unroll
    for (int k = 0; k < 9; ++k) dt[e][k] = 0.f;
  }
#pragma unroll
  for (int r = 0; r < 3; ++r)
#pragma unroll
    for (int i = 0; i < 6; ++i) s2[r][i] = 0.f;

#pragma unroll 4
  for (int cc = 0; cc < 16; ++cc) {
    const float* cb = nbase + (size_t)(c0 + cc) * HW;
    const float4 am = *(const float4*)(cb + oM + x0);
    const float4 ac = *(const float4*)(cb + oC + x0);
    const float4 ap = *(const float4*)(cb + oP + x0);
    const float4 rf = *(const float4*)(rrow + (size_t)(c0 + cc) * HW + x0);
    const float rfe[4] = {rf.x, rf.y, rf.z, rf.w};
    sr[0] = fmaf(rfe[0], rfe[0], sr[0]);
    sr[1] = fmaf(rfe[1], rfe[1], sr[1]);
    sr[2] = fmaf(rfe[2], rfe[2], sr[2]);
    sr[3] = fmaf(rfe[3], rfe[3], sr[3]);
    const float4 rows[3] = {am, ac, ap};
#pragma unroll
    for (int r = 0; r < 3; ++r) {
      const float4 v = rows[r];
      float L = __shfl(v.w, lane - 1);
      float R = __shfl(v.x, lane + 1);
      if (lane == 0)  L = v.y;        // reflect: x=-1 -> 1
      if (lane == 63) R = v.z;        // reflect: x=256 -> 254
      const float win[6] = {L, v.x, v.y, v.z, v.w, R};
#pragma unroll
      for (int i = 0; i < 6; ++i) s2[r][i] = fmaf(win[i], win[i], s2[r][i]);
      const int kb = r * 3;
#pragma unroll
      for (int e = 0; e < 4; ++e)
#pragma unroll
        for (int cx = 0; cx < 3; ++cx)
          dt[e][kb + cx] = fmaf(rfe[e], win[e + cx], dt[e][kb + cx]);
    }
  }

  // ---- write 19 partial planes (coalesced float4) ----
  const int base = by * W + x0;       // pixel base
#pragma unroll
  for (int k = 0; k < 9; ++k)
    *(float4*)&ws[(size_t)(q * 19 + k) * PIX + base] = float4{dt[0][k], dt[1][k], dt[2][k], dt[3][k]};
#pragma unroll
  for (int k = 0; k < 9; ++k) {
    const int r = k / 3, cx = k % 3;   // sq[e][k] = s2[r][e+cx]
    *(float4*)&ws[(size_t)(q * 19 + 9 + k) * PIX + base] =
        float4{s2[r][cx], s2[r][cx + 1], s2[r][cx + 2], s2[r][cx + 3]};
  }
  *(float4*)&ws[(size_t)(q * 19 + 18) * PIX + base] = float4{sr[0], sr[1], sr[2], sr[3]};
}

// ---------------- K2: reduce + softmax kernel ----------------
__global__ __launch_bounds__(256) void reduce_kernel(float* __restrict__ ws) {
  const int tid = threadIdx.x;
  const int by  = ((blockIdx.x & 7) << 6) | (blockIdx.x >> 3);   // bijective on [0,512)
  const int pix = by * W + tid;

  float td[9], tq[9];
#pragma unroll
  for (int k = 0; k < 9; ++k) {
    td[k] = ws[(size_t)(0 * 19 + k) * PIX + pix] + ws[(size_t)(1 * 19 + k) * PIX + pix]
          + ws[(size_t)(2 * 19 + k) * PIX + pix] + ws[(size_t)(3 * 19 + k) * PIX + pix];
    tq[k] = ws[(size_t)(0 * 19 + 9 + k) * PIX + pix] + ws[(size_t)(1 * 19 + 9 + k) * PIX + pix]
          + ws[(size_t)(2 * 19 + 9 + k) * PIX + pix] + ws[(size_t)(3 * 19 + 9 + k) * PIX + pix];
  }
  const float tsr = ws[(size_t)(0 * 19 + 18) * PIX + pix] + ws[(size_t)(1 * 19 + 18) * PIX + pix]
                  + ws[(size_t)(2 * 19 + 18) * PIX + pix] + ws[(size_t)(3 * 19 + 18) * PIX + pix];

  const float invr = __frsqrt_rn(fmaxf(tsr, 1e-24f));
  float d[9], invp[9];
  float mx = -INFINITY;
#pragma unroll
  for (int k = 0; k < 9; ++k) {
    invp[k] = __frsqrt_rn(fmaxf(tq[k], 1e-24f));
    d[k]    = td[k] * invr * invp[k];
    mx      = fmaxf(mx, d[k]);
  }
  float s = 0.f;
  float cfv[9];
#pragma unroll
  for (int k = 0; k < 9; ++k) {
    cfv[k] = __expf(d[k] - mx);
    s += cfv[k];
  }
  const float sinv = 1.0f / s;
  // overwrite q=0 dt planes with coefs (read-before-write per thread; pixels disjoint)
#pragma unroll
  for (int k = 0; k < 9; ++k)
    ws[(size_t)k * PIX + pix] = cfv[k] * sinv * invp[k];   // patch l2norm folded
}

// ---------------- K3: apply kernel (proven; XCD swizzle, grid=4096) ----------------
__global__ __launch_bounds__(256) void apply_kernel(const float* __restrict__ nbr,
                                                    const float* __restrict__ ref,
                                                    const float* __restrict__ coef,
                                                    float* __restrict__ out) {
  const int blk  = ((blockIdx.x & 7) << 9) | (blockIdx.x >> 3);  // bijective on [0,4096)
  const int gid  = blk * 256 + threadIdx.x;
  const int lane = gid & 63;
  const int x0   = lane * 4;
  const int t    = gid >> 6;
  const int y    = t & 255;
  const int u    = t >> 8;
  const int b    = u >> 5;
  const int c0   = (u & 31) * 2;

  const int ym = (y == 0)     ? 1     : y - 1;
  const int yp = (y == H - 1) ? H - 2 : y + 1;

  const float* n0  = nbr + ((size_t)b * C + c0) * HW;
  const float* n1  = n0 + HW;
  const float* r0p = ref + ((size_t)b * C + c0) * HW;
  float*       o0  = out + ((size_t)b * C + c0) * HW;

  const float4 a0 = *(const float4*)(n0 + ym * W + x0);
  const float4 a1 = *(const float4*)(n0 + y  * W + x0);
  const float4 a2 = *(const float4*)(n0 + yp * W + x0);
  const float4 b0 = *(const float4*)(n1 + ym * W + x0);
  const float4 b1 = *(const float4*)(n1 + y  * W + x0);
  const float4 b2 = *(const float4*)(n1 + yp * W + x0);
  const float4 f0 = *(const float4*)(r0p + y * W + x0);
  const float4 f1 = *(const float4*)(r0p + HW + y * W + x0);

  float La0 = __shfl(a0.w, lane - 1), Ra0 = __shfl(a0.x, lane + 1);
  float La1 = __shfl(a1.w, lane - 1), Ra1 = __shfl(a1.x, lane + 1);
  float La2 = __shfl(a2.w, lane - 1), Ra2 = __shfl(a2.x, lane + 1);
  float Lb0 = __shfl(b0.w, lane - 1), Rb0 = __shfl(b0.x, lane + 1);
  float Lb1 = __shfl(b1.w, lane - 1), Rb1 = __shfl(b1.x, lane + 1);
  float Lb2 = __shfl(b2.w, lane - 1), Rb2 = __shfl(b2.x, lane + 1);
  if (lane == 0)  { La0 = a0.y; La1 = a1.y; La2 = a2.y; Lb0 = b0.y; Lb1 = b1.y; Lb2 = b2.y; }
  if (lane == 63) { Ra0 = a0.z; Ra1 = a1.z; Ra2 = a2.z; Rb0 = b0.z; Rb1 = b1.z; Rb2 = b2.z; }

  float va[3][6] = {{La0, a0.x, a0.y, a0.z, a0.w, Ra0},
                    {La1, a1.x, a1.y, a1.z, a1.w, Ra1},
                    {La2, a2.x, a2.y, a2.z, a2.w, Ra2}};
  float vb[3][6] = {{Lb0, b0.x, b0.y, b0.z, b0.w, Rb0},
                    {Lb1, b1.x, b1.y, b1.z, b1.w, Rb1},
                    {Lb2, b2.x, b2.y, b2.z, b2.w, Rb2}};

  const int cbase = b * HW + y * W + x0;
  float aga[4] = {0.f, 0.f, 0.f, 0.f};
  float agb[4] = {0.f, 0.f, 0.f, 0.f};
#pragma unroll
  for (int k = 0; k < 9; ++k) {
    const float4 cf = *(const float4*)(coef + (size_t)k * PIX + cbase);
    const int r  = k / 3;
    const int cx = k % 3;
    const float cfe[4] = {cf.x, cf.y, cf.z, cf.w};
#pragma unroll
    for (int e = 0; e < 4; ++e) {
      aga[e] = fmaf(cfe[e], va[r][e + cx], aga[e]);
      agb[e] = fmaf(cfe[e], vb[r][e + cx], agb[e]);
    }
  }

  const float ctra[4] = {a1.x, a1.y, a1.z, a1.w};
  const float ctrb[4] = {b1.x, b1.y, b1.z, b1.w};
  const float rfa[4]  = {f0.x, f0.y, f0.z, f0.w};
  const float rfb[4]  = {f1.x, f1.y, f1.z, f1.w};
  float oae[4], obe[4];
#pragma unroll
  for (int e = 0; e < 4; ++e) {
    const float da = ctra[e] - rfa[e];
    const float db = ctrb[e] - rfb[e];
    oae[e] = aga[e] * __expf(-(da * da));
    obe[e] = agb[e] * __expf(-(db * db));
  }
  float4 oa, ob4;
  oa.x = oae[0]; oa.y = oae[1]; oa.z = oae[2]; oa.w = oae[3];
  ob4.x = obe[0]; ob4.y = obe[1]; ob4.z = obe[2]; ob4.w = obe[3];

  *(float4*)(o0 + y * W + x0) = oa;
  *(float4*)(o0 + HW + y * W + x0) = ob4;
}

// ---------------- fallback: R19 fused kernel (31us, proven) ----------------
__global__ __launch_bounds__(256, 2) void fused_kernel(const float* __restrict__ nbr,
                                                       const float* __restrict__ ref,
                                                       float* __restrict__ out) {
  __shared__ float buf[10][4][W];

  const int tid  = threadIdx.x;
  const int lane = tid & 63;
  const int wv   = tid >> 6;
  const int x0   = lane * 4;

  const int by = ((blockIdx.x & 7) << 6) | (blockIdx.x >> 3);
  const int b  = by >> 8;
  const int y  = by & 255;
  const int ym = (y == 0)     ? 1     : y - 1;
  const int yp = (y == H - 1) ? H - 2 : y + 1;

  const float* nbase = nbr + (size_t)b * C * HW;
  const float* rrow  = ref + (size_t)b * C * HW + y * W;
  float*       obase = out + (size_t)b * C * HW + y * W;
  const int oM = ym * W, oC = y * W, oP = yp * W;
  const int c0 = wv * 16;

  float dt[4][9], s2[3][6], sr[4];
#pragma unroll
  for (int e = 0; e < 4; ++e) {
    sr[e] = 0.f;
#pragma unroll
    for (int k = 0; k < 9; ++k) dt[e][k] = 0.f;
  }
#pragma unroll
  for (int r = 0; r < 3; ++r)
#pragma unroll
    for (int i = 0; i < 6; ++i) s2[r][i] = 0.f;

#pragma unroll 4
  for (int cc = 0; cc < 16; ++cc) {
    const float* cb = nbase + (size_t)(c0 + cc) * HW;
    const float4 am = *(const float4*)(cb + oM + x0);
    const float4 ac = *(const float4*)(cb + oC + x0);
    const float4 ap = *(const float4*)(cb + oP + x0);
    const float4 rf = *(const float4*)(rrow + (size_t)(c0 + cc) * HW + x0);
    const float rfe[4] = {rf.x, rf.y, rf.z, rf.w};
    sr[0] = fmaf(rfe[0], rfe[0], sr[0]);
    sr[1] = fmaf(rfe[1], rfe[1], sr[1]);
    sr[2] = fmaf(rfe[2], rfe[2], sr[2]);
    sr[3] = fmaf(rfe[3], rfe[3], sr[3]);
    const float4 rows[3] = {am, ac, ap};
#pragma unroll
    for (int r = 0; r < 3; ++r) {
      const float4 v = rows[r];
      float L = __shfl(v.w, lane - 1);
      float R = __shfl(v.x, lane + 1);
      if (lane == 0)  L = v.y;
      if (lane == 63) R = v.z;
      const float win[6] = {L, v.x, v.y, v.z, v.w, R};
#pragma unroll
      for (int i = 0; i < 6; ++i) s2[r][i] = fmaf(win[i], win[i], s2[r][i]);
      const int kb = r * 3;
#pragma unroll
      for (int e = 0; e < 4; ++e)
#pragma unroll
        for (int cx = 0; cx < 3; ++cx)
          dt[e][kb + cx] = fmaf(rfe[e], win[e + cx], dt[e][kb + cx]);
    }
  }

#pragma unroll
  for (int k = 0; k < 9; ++k)
    *(float4*)&buf[k][wv][x0] = float4{dt[0][k], dt[1][k], dt[2][k], dt[3][k]};
  *(float4*)&buf[9][wv][x0] = float4{sr[0], sr[1], sr[2], sr[3]};
  __syncthreads();

  float td[9];
#pragma unroll
  for (int k = 0; k < 9; ++k)
    td[k] = buf[k][0][tid] + buf[k][1][tid] + buf[k][2][tid] + buf[k][3][tid];
  const float tsr = buf[9][0][tid] + buf[9][1][tid] + buf[9][2][tid] + buf[9][3][tid];
  __syncthreads();

#pragma unroll
  for (int k = 0; k < 9; ++k) {
    const int r = k / 3, cx = k % 3;
    *(float4*)&buf[k][wv][x0] = float4{s2[r][cx], s2[r][cx + 1], s2[r][cx + 2], s2[r][cx + 3]};
  }
  __syncthreads();

  float tq[9];
#pragma unroll
  for (int k = 0; k < 9; ++k)
    tq[k] = buf[k][0][tid] + buf[k][1][tid] + buf[k][2][tid] + buf[k][3][tid];

  const float invr = __frsqrt_rn(fmaxf(tsr, 1e-24f));
  float d[9], invp[9];
  float mx = -INFINITY;
#pragma unroll
  for (int k = 0; k < 9; ++k) {
    invp[k] = __frsqrt_rn(fmaxf(tq[k], 1e-24f));
    d[k]    = td[k] * invr * invp[k];
    mx      = fmaxf(mx, d[k]);
  }
  float s = 0.f;
  float cfv[9];
#pragma unroll
  for (int k = 0; k < 9; ++k) {
    cfv[k] = __expf(d[k] - mx);
    s += cfv[k];
  }
  const float sinv = 1.0f / s;

  __syncthreads();
  float* wc = &buf[0][0][0];
#pragma unroll
  for (int k = 0; k < 9; ++k)
    wc[k * W + tid] = cfv[k] * sinv * invp[k];
  __syncthreads();

  float4 cf4[9];
#pragma unroll
  for (int k = 0; k < 9; ++k) cf4[k] = *(const float4*)&wc[k * W + x0];

#pragma unroll 2
  for (int cc = 0; cc < 16; ++cc) {
    const int c = c0 + cc;
    const float* cb = nbase + (size_t)c * HW;
    const float4 am = *(const float4*)(cb + oM + x0);
    const float4 ac = *(const float4*)(cb + oC + x0);
    const float4 ap = *(const float4*)(cb + oP + x0);
    const float4 rf = *(const float4*)(rrow + (size_t)c * HW + x0);

    float agg[4] = {0.f, 0.f, 0.f, 0.f};
    const float4 rows[3] = {am, ac, ap};
#pragma unroll
    for (int r = 0; r < 3; ++r) {
      const float4 v = rows[r];
      float L = __shfl(v.w, lane - 1);
      float R = __shfl(v.x, lane + 1);
      if (lane == 0)  L = v.y;
      if (lane == 63) R = v.z;
      const float win[6] = {L, v.x, v.y, v.z, v.w, R};
#pragma unroll
      for (int cx = 0; cx < 3; ++cx) {
        const float4 cf = cf4[r * 3 + cx];
        const float cfe[4] = {cf.x, cf.y, cf.z, cf.w};
#pragma unroll
        for (int e = 0; e < 4; ++e)
          agg[e] = fmaf(cfe[e], win[e + cx], agg[e]);
      }
    }
    const float ctr[4] = {ac.x, ac.y, ac.z, ac.w};
    const float rfe[4] = {rf.x, rf.y, rf.z, rf.w};
    float oe[4];
#pragma unroll
    for (int e = 0; e < 4; ++e) {
      const float da = ctr[e] - rfe[e];
      oe[e] = agg[e] * __expf(-(da * da));
    }
    float4 o4;
    o4.x = oe[0]; o4.y = oe[1]; o4.z = oe[2]; o4.w = oe[3];
    *(float4*)(obase + (size_t)c * HW + x0) = o4;
  }
}

extern "C" void kernel_launch(void* const* d_in, const int* in_sizes, int n_in,
                              void* d_out, int out_size, void* d_ws, size_t ws_size,
                              hipStream_t stream) {
  const float* nbr = (const float*)d_in[0];
  const float* ref = (const float*)d_in[1];
  float*       out = (float*)d_out;
  const size_t need = (size_t)4 * 19 * PIX * sizeof(float);   // 39.8 MB partials

  if (ws_size >= need) {
    float* ws = (float*)d_ws;
    partial_kernel<<<dim3(2048), dim3(64), 0, stream>>>(nbr, ref, ws);
    reduce_kernel<<<dim3(512), dim3(256), 0, stream>>>(ws);
    apply_kernel<<<dim3(PIX / 4 * (C / 2) / 256), dim3(256), 0, stream>>>(nbr, ref, ws, out);
  } else {
    fused_kernel<<<dim3(B * H), dim3(256), 0, stream>>>(nbr, ref, out);
  }
}